// Round 4
// baseline (1518.127 us; speedup 1.0000x reference)
//
#include <hip/hip_runtime.h>

#define THREADS 128   // one sample per block: 128 lanes = 128 gate rows, 2 waves

// fast reciprocal (v_rcp_f32, ~1 ulp) — IEEE divide costs ~10 VALU ops without fast-math
__device__ __forceinline__ float frcp(float x){ return __builtin_amdgcn_rcpf(x); }
__device__ __forceinline__ float fsig(float x){ return frcp(1.0f + __expf(-x)); }
// tanh = 1 - 2/(e^{2x}+1): e->inf gives 1, e->0 gives -1; no clamp needed
__device__ __forceinline__ float ftanh(float x){
    float e = __expf(2.0f * x);
    return fmaf(-2.0f, frcp(e + 1.0f), 1.0f);
}
// NaN-PROPAGATING leaky relu
__device__ __forceinline__ float lrelu(float x){ return x > 0.0f ? x : 0.01f * x; }

__global__ void diag_kernel(float* outp, float code){ outp[0] = code; }

// One LSTM layer, 1 gate row per lane (g = tid, 0..127), replicated cell state.
// whh_row = whh + g*32 (row g register-resident: 32 VGPRs).
// acc[t] = xg[t][g] + biases (in regs). h_t published to hout[t*32+j].
// Per t: dot(wh,h) -> act(own gate) -> abuf[g] -> barrier -> all lanes read 4 acts,
// update replicated c, compute h -> lanes<32 publish -> barrier.
// s1/s2 accumulate Sum(h), Sum(h^2) over own j across t (each j replicated 4x,
// so a single 64-lane wave reduce yields 2*Sum_total -> caller scales by 1/320).
__device__ __forceinline__ void lstm_layer(const float* __restrict__ whh_row,
                                           float (&acc)[5],
                                           float* __restrict__ hout,   // 160 floats
                                           float* __restrict__ abuf,   // 128 floats
                                           int g, int j,
                                           float ak, float aa, float ab,
                                           float& s1o, float& s2o)
{
    float wh[32];
    #pragma unroll
    for (int q = 0; q < 8; ++q){
        float4 v = *(const float4*)(whh_row + q*4);
        wh[q*4+0]=v.x; wh[q*4+1]=v.y; wh[q*4+2]=v.z; wh[q*4+3]=v.w;
    }
    float c = 0.0f, s1 = 0.0f, s2 = 0.0f;
    #pragma unroll
    for (int t = 0; t < 5; ++t){
        float qa = acc[t], qb = 0.0f, qc = 0.0f, qd = 0.0f;
        if (t > 0){
            const float* hp = hout + (t-1)*32;
            #pragma unroll
            for (int k0 = 0; k0 < 32; k0 += 8){
                float4 h0 = *(const float4*)(hp + k0);      // broadcast, conflict-free
                float4 h1 = *(const float4*)(hp + k0 + 4);
                qa = fmaf(wh[k0+0], h0.x, qa);  qb = fmaf(wh[k0+1], h0.y, qb);
                qc = fmaf(wh[k0+2], h0.z, qc);  qd = fmaf(wh[k0+3], h0.w, qd);
                qa = fmaf(wh[k0+4], h1.x, qa);  qb = fmaf(wh[k0+5], h1.y, qb);
                qc = fmaf(wh[k0+6], h1.z, qc);  qd = fmaf(wh[k0+7], h1.w, qd);
            }
        }
        float qs = (qa + qb) + (qc + qd);
        // own gate activation: sigma for i,f,o; tanh (=2*sigma(2x)-1) for g~
        abuf[g] = fmaf(aa, fsig(ak * qs), ab);
        __syncthreads();
        float ai = abuf[     j];   // lanes j and 32+j read same addr -> broadcast
        float af = abuf[32 + j];
        float ag = abuf[64 + j];
        float ao = abuf[96 + j];
        c = fmaf(af, c, ai * ag);          // replicated x4 across q -> identical
        float h = ao * ftanh(c);
        s1 += h; s2 = fmaf(h, h, s2);
        if (g < 32) hout[t*32 + j] = h;
        __syncthreads();
    }
    s1o = s1; s2o = s2;
}

// NOTE (empirical R0-R3): waves/SIMD = floor(256/VGPR) on this setup. Target VGPR<=64
// for 4 waves/SIMD. Do NOT set min-waves launch bound ((256,4) caused a 64-VGPR clamp
// with scratch spills in R1); keep natural pressure low instead: 1 gate/lane = wh[32].
__global__ __launch_bounds__(THREADS, 1)
void reslstm_kernel(const float* __restrict__ data,
                    const float* __restrict__ wih0, const float* __restrict__ whh0,
                    const float* __restrict__ bih0, const float* __restrict__ bhh0,
                    const float* __restrict__ g0p,  const float* __restrict__ be0p,
                    const float* __restrict__ wih1, const float* __restrict__ whh1,
                    const float* __restrict__ bih1, const float* __restrict__ bhh1,
                    const float* __restrict__ g1p,  const float* __restrict__ be1p,
                    const float* __restrict__ dwp,  const float* __restrict__ dbp,
                    float* __restrict__ outp, int Btot)
{
    // Tiny LDS (~2.4 KB) -> occupancy limited by VGPR only.
    __shared__ __attribute__((aligned(16))) float xs[320];    // x [t][64] (pad n=62,63=0); reused as layer-1 h
    __shared__ __attribute__((aligned(16))) float obuf[160];  // layer-0 h, then out0 (post LN+lrelu)
    __shared__ __attribute__((aligned(16))) float abuf[128];  // per-t gate activations

    const int tid = threadIdx.x;
    const int b   = blockIdx.x;          // one sample per block; grid == Btot
    const int g   = tid;                 // gate row 0..127 (0-31 i, 32-63 f, 64-95 g~, 96-127 o)
    const int j   = g & 31;              // hidden unit
    const bool isg = (g >= 64) && (g < 96);
    const float ak = isg ? 2.0f : 1.0f;  // act(x) = aa*sigma(ak*x)+ab
    const float aa = isg ? 2.0f : 1.0f;
    const float ab = isg ? -1.0f : 0.0f;

    // ---------------- stage x (coalesced): xs[t*64+n] = dat[n*5+t] ----------------
    {
        const float* dat = data + (size_t)b * 310;
        for (int i = tid; i < 310; i += THREADS){
            int n = i / 5, t = i - n*5;
            xs[t*64 + n] = dat[i];
        }
        if (tid < 10) xs[(tid>>1)*64 + 62 + (tid&1)] = 0.0f;   // zero pad n=62,63
    }
    __syncthreads();

    // ---------------- phase A: acc[t] = x_t . wih0[g] + bih0[g]+bhh0[g] ----------------
    float acc[5];
    {
        float bv = bih0[g] + bhh0[g];                 // L1/L2-hot per-lane loads
        #pragma unroll
        for (int t = 0; t < 5; ++t) acc[t] = bv;
        const float* wr = wih0 + (size_t)g * 62;      // row is 8B-aligned (248 B stride)
        #pragma unroll
        for (int n0 = 0; n0 < 60; n0 += 4){
            float2 wa = *(const float2*)(wr + n0);
            float2 wb = *(const float2*)(wr + n0 + 2);
            #pragma unroll
            for (int t = 0; t < 5; ++t){
                float4 xv = *(const float4*)(xs + t*64 + n0);   // broadcast
                acc[t] = fmaf(wa.x, xv.x, fmaf(wa.y, xv.y,
                         fmaf(wb.x, xv.z, fmaf(wb.y, xv.w, acc[t]))));
            }
        }
        float2 wt = *(const float2*)(wr + 60);        // tail n=60,61 (do NOT read past row)
        #pragma unroll
        for (int t = 0; t < 5; ++t){
            float2 xv = *(const float2*)(xs + t*64 + 60);
            acc[t] = fmaf(wt.x, xv.x, fmaf(wt.y, xv.y, acc[t]));
        }
    }

    // ---------------- layer 0 recurrence + LN + LeakyReLU ----------------
    {
        float s1, s2;
        lstm_layer(whh0 + (size_t)g*32, acc, obuf, abuf, g, j, ak, aa, ab, s1, s2);
        #pragma unroll
        for (int m = 1; m <= 32; m <<= 1){
            s1 += __shfl_xor(s1, m, 64);
            s2 += __shfl_xor(s2, m, 64);
        }
        float mu   = s1 * (1.0f/320.0f);   // 64-lane reduce double-counts each (t,j)
        float var  = s2 * (1.0f/320.0f) - mu*mu;
        float rstd = rsqrtf(var + 1e-5f);
        // in-place write-back: idx=tid (all lanes) and idx=128+tid (lanes<32)
        {
            float v = obuf[tid];
            obuf[tid] = lrelu(fmaf((v - mu)*rstd, g0p[tid], be0p[tid]));
            if (tid < 32){
                float v2 = obuf[128 + tid];
                obuf[128 + tid] = lrelu(fmaf((v2 - mu)*rstd, g0p[128 + tid], be0p[128 + tid]));
            }
        }
    }
    __syncthreads();

    // ---------------- phase B: acc[t] = out0_t . wih1[g] + bih1[g]+bhh1[g] ----------------
    {
        float bv = bih1[g] + bhh1[g];
        #pragma unroll
        for (int t = 0; t < 5; ++t) acc[t] = bv;
        const float* wr = wih1 + (size_t)g * 32;      // 128 B stride, 16B-aligned
        #pragma unroll
        for (int k0 = 0; k0 < 32; k0 += 4){
            float4 w = *(const float4*)(wr + k0);
            #pragma unroll
            for (int t = 0; t < 5; ++t){
                float4 ov = *(const float4*)(obuf + t*32 + k0);  // broadcast
                acc[t] = fmaf(w.x, ov.x, fmaf(w.y, ov.y,
                         fmaf(w.z, ov.z, fmaf(w.w, ov.w, acc[t]))));
            }
        }
    }

    // ---------------- layer 1 recurrence + LN + residual + head ----------------
    float* h1 = xs;   // xs dead after phase A -> reuse (needs 160 of 320 words)
    {
        float s1, s2;
        lstm_layer(whh1 + (size_t)g*32, acc, h1, abuf, g, j, ak, aa, ab, s1, s2);
        #pragma unroll
        for (int m = 1; m <= 32; m <<= 1){
            s1 += __shfl_xor(s1, m, 64);
            s2 += __shfl_xor(s2, m, 64);
        }
        float mu   = s1 * (1.0f/320.0f);
        float var  = s2 * (1.0f/320.0f) - mu*mu;
        float rstd = rsqrtf(var + 1e-5f);
        // write-back o1 = lrelu(LN(h1)) + out0 (residual), in place in h1
        {
            float v = h1[tid];
            h1[tid] = lrelu(fmaf((v - mu)*rstd, g1p[tid], be1p[tid])) + obuf[tid];
            if (tid < 32){
                float v2 = h1[128 + tid];
                h1[128 + tid] = lrelu(fmaf((v2 - mu)*rstd, g1p[128 + tid], be1p[128 + tid]))
                              + obuf[128 + tid];
            }
        }
    }
    __syncthreads();

    // ---------------- dense head: (160) @ dw^T + db, LeakyReLU ----------------
    if (g < 32){   // lanes 0..31 of wave 0; no barriers below
        float p0 = 0.0f, p1 = 0.0f, p2 = 0.0f;
        #pragma unroll
        for (int t = 0; t < 5; ++t){
            float v = h1[t*32 + j];
            p0 = fmaf(dwp[      t*32 + j], v, p0);
            p1 = fmaf(dwp[160 + t*32 + j], v, p1);
            p2 = fmaf(dwp[320 + t*32 + j], v, p2);
        }
        #pragma unroll
        for (int m = 1; m <= 16; m <<= 1){
            p0 += __shfl_xor(p0, m, 64);
            p1 += __shfl_xor(p1, m, 64);
            p2 += __shfl_xor(p2, m, 64);
        }
        if (j == 0){
            size_t o = (size_t)b * 3;
            outp[o + 0] = lrelu(p0 + dbp[0]);
            outp[o + 1] = lrelu(p1 + dbp[1]);
            outp[o + 2] = lrelu(p2 + dbp[2]);
        }
    }
}

extern "C" void kernel_launch(void* const* d_in, const int* in_sizes, int n_in,
                              void* d_out, int out_size, void* d_ws, size_t ws_size,
                              hipStream_t stream)
{
    (void)d_ws; (void)ws_size;

    const int B = out_size / 3;

    // Locate 'data' = largest input; infer the harness's input ordering from it.
    int idx_data = 0;
    for (int i = 1; i < n_in; ++i)
        if (in_sizes[i] > in_sizes[idx_data]) idx_data = i;

    // semantic slots (reference dict order):
    // 0 data,1 wih0,2 whh0,3 bih0,4 bhh0,5 g0,6 be0,7 wih1,8 whh1,9 bih1,
    // 10 bhh1,11 g1,12 be1,13 dw,14 db
    static const int dict_map[15]  = {0,1,2,3,4,5,6,7,8,9,10,11,12,13,14};
    // alphabetical key order fallback
    static const int alpha_map[15] = {6,13,11,2,0,9,4,14,12,3,1,10,5,8,7};
    static const int rev_map[15]   = {14,13,12,11,10,9,8,7,6,5,4,3,2,1,0};

    const int* map = dict_map;
    if (idx_data == 6)       map = alpha_map;
    else if (idx_data == 14) map = rev_map;

    long ds  = (long)in_sizes[idx_data];
    long ws0 = (long)in_sizes[map[1]];
    bool ok = (ds == (long)B*310 || ds == (long)B*620 || ds == (long)B*1240)
           && (ws0 == 7936 || ws0 == 15872 || ws0 == 31744);

    if (!ok || B <= 0){
        diag_kernel<<<1, 1, 0, stream>>>((float*)d_out, 100.0f + 10.0f*idx_data);
        return;
    }

    const float* P[15];
    for (int k = 0; k < 15; ++k) P[k] = (const float*)d_in[map[k]];

    reslstm_kernel<<<dim3(B), dim3(THREADS), 0, stream>>>(
        P[0], P[1], P[2], P[3], P[4], P[5], P[6], P[7], P[8], P[9],
        P[10], P[11], P[12], P[13], P[14],
        (float*)d_out, B);
}